// Round 1
// baseline (419.404 us; speedup 1.0000x reference)
//
#include <hip/hip_runtime.h>
#include <math.h>

// EdgeEmbedding: pos[2048,3] f32 -> (dist_edge[N,N,20], dir_edge[N,N,3], mask[N,N]) f32, flat-concat in d_out.
// Streaming-write-bound: 402 MB stored per launch (harness poisons d_out, zeros must be written).

#define NATOMS 2048
#define NBASIS 20
#define RCUT   5.0f

__global__ __launch_bounds__(256) void edge_embed_kernel(
    const float* __restrict__ pos, float* __restrict__ out)
{
    const int t = threadIdx.x;
    const int i = blockIdx.x >> 3;               // 8 blocks of 256 threads per row i -> i wave-uniform
    const int j = ((blockIdx.x & 7) << 8) | t;   // consecutive j across the block -> coalesced

    const float xi = pos[3 * i + 0], yi = pos[3 * i + 1], zi = pos[3 * i + 2];
    const float xj = pos[3 * j + 0], yj = pos[3 * j + 1], zj = pos[3 * j + 2];

    const float dx = xi - xj, dy = yi - yj, dz = zi - zj;
    float d2;
    {
        // Match numpy's unfused mul-then-add rounding so the dist<r mask is bit-identical:
        // a 1-ulp flip at the boundary costs up to 1.0 on dir_edge.
#pragma clang fp contract(off)
        d2 = (dx * dx + dy * dy) + dz * dz;
    }
    const float dist = sqrtf(d2);
    const bool m = (dist < RCUT) && (i != j);

    const long long pair = (long long)i * NATOMS + j;
    float* __restrict__ de  = out + pair * NBASIS;
    float* __restrict__ dir = out + (long long)NATOMS * NATOMS * NBASIS + pair * 3;
    float* __restrict__ mk  = out + (long long)NATOMS * NATOMS * (NBASIS + 3) + pair;

    float vals[NBASIS];
#pragma unroll
    for (int k = 0; k < NBASIS; ++k) vals[k] = 0.0f;
    float dirx = 0.0f, diry = 0.0f, dirz = 0.0f, mv = 0.0f;

    if (m) {  // ~0.8% of lanes; ~40% of waves enter with a sparse exec mask
        dirx = dx / dist; diry = dy / dist; dirz = dz / dist;
        mv = 1.0f;
        const float x  = dist / RCUT;
        // PolynomialCutoff p=9: 1 - 55 x^9 + 99 x^10 - 45 x^11
        const float x2 = x * x, x4 = x2 * x2, x8 = x4 * x4, x9 = x8 * x;
        const float env = 1.0f - 55.0f * x9 + 99.0f * x9 * x - 45.0f * x9 * x2;
        // RadialBessel: env * sin(k*pi*x)/x, k=1..20 via Chebyshev recurrence
        const float theta = 3.14159265358979323846f * x;
        const float s1 = sinf(theta);
        const float c1 = cosf(theta);
        const float twoc  = 2.0f * c1;
        const float scale = env / x;
        float pm2 = 0.0f, pm1 = s1;
        vals[0] = scale * s1;
#pragma unroll
        for (int k = 1; k < NBASIS; ++k) {
            const float sk = twoc * pm1 - pm2;
            vals[k] = scale * sk;
            pm2 = pm1; pm1 = sk;
        }
    }

    // dist_edge: pair stride = 20 floats = 80 B -> 16B-aligned, 5 float4 stores
    float4* __restrict__ deq = (float4*)de;
#pragma unroll
    for (int q = 0; q < 5; ++q)
        deq[q] = make_float4(vals[4 * q + 0], vals[4 * q + 1], vals[4 * q + 2], vals[4 * q + 3]);
    dir[0] = dirx; dir[1] = diry; dir[2] = dirz;
    *mk = mv;
}

extern "C" void kernel_launch(void* const* d_in, const int* in_sizes, int n_in,
                              void* d_out, int out_size, void* d_ws, size_t ws_size,
                              hipStream_t stream) {
    const float* pos = (const float*)d_in[0];
    float* out = (float*)d_out;
    // 2048 rows * 8 blocks/row = 16384 blocks of 256 threads, one thread per (i,j) pair
    edge_embed_kernel<<<dim3(NATOMS * 8), dim3(256), 0, stream>>>(pos, out);
}

// Round 2
// 395.627 us; speedup vs baseline: 1.0601x; 1.0601x over previous
//
#include <hip/hip_runtime.h>
#include <math.h>

// EdgeEmbedding: pos[2048,3] f32 -> (dist_edge[N,N,20], dir_edge[N,N,3], mask[N,N]) f32 flat in d_out.
// Streaming-write-bound: 402 MB stored per launch. R1 lesson: coalescing is per store
// INSTRUCTION — 1 thread/pair gave lane-stride-80B dwordx4 stores (~80 lines/instr, 5x
// transaction inflation, 419 us). Now 5 threads/pair: lane-stride-16B -> minimal lines/instr.

#define NATOMS 2048
#define NBASIS 20
#define RCUT   5.0f
#define PAIRS_PER_BLOCK 64
#define BLOCK_THREADS   320   // 64 pairs * 5 quad-slots; addr = base + 16*t, contiguous per wave

__global__ __launch_bounds__(BLOCK_THREADS) void edge_embed_kernel(
    const float* __restrict__ pos, float* __restrict__ out)
{
    const int t = threadIdx.x;
    const int blocksPerRow = NATOMS / PAIRS_PER_BLOCK;          // 32
    const int i  = blockIdx.x / blocksPerRow;                   // wave-uniform
    const int j0 = (blockIdx.x % blocksPerRow) * PAIRS_PER_BLOCK;

    const int p = t / 5;            // pair slot 0..63
    const int q = t - 5 * p;        // quad 0..4 (k = 4q+1 .. 4q+4)
    const int j = j0 + p;

    const float xi = pos[3 * i + 0], yi = pos[3 * i + 1], zi = pos[3 * i + 2];
    const float xj = pos[3 * j + 0], yj = pos[3 * j + 1], zj = pos[3 * j + 2];
    const float dx = xi - xj, dy = yi - yj, dz = zi - zj;
    float d2;
    {
        // match numpy's unfused rounding so the dist<r mask can't flip at the boundary
#pragma clang fp contract(off)
        d2 = (dx * dx + dy * dy) + dz * dz;
    }
    const float dist = sqrtf(d2);
    const bool m = (dist < RCUT) && (i != j);

    float4 v = make_float4(0.0f, 0.0f, 0.0f, 0.0f);
    if (m) {   // ~0.8% of lanes
        const float x  = dist * (1.0f / RCUT);
        const float x2 = x * x, x4 = x2 * x2, x8 = x4 * x4, x9 = x8 * x;
        const float env = 1.0f - 55.0f * x9 + 99.0f * x9 * x - 45.0f * x9 * x2;
        const float scale = env / x;
        const float theta = 3.14159265358979323846f * x;
        const float k0 = (float)(4 * q + 1);
        const float s0 = sinf(k0 * theta);
        const float s1 = sinf((k0 + 1.0f) * theta);
        const float twoc = 2.0f * cosf(theta);
        const float s2 = twoc * s1 - s0;
        const float s3 = twoc * s2 - s1;
        v = make_float4(scale * s0, scale * s1, scale * s2, scale * s3);
    }

    const long long pair = (long long)i * NATOMS + j;
    float4* __restrict__ de = (float4*)out;
    de[pair * 5 + q] = v;   // = quad index pair0*5 + t -> contiguous 16B per lane

    if (t < PAIRS_PER_BLOCK) {
        // wave 0: dir (3 dwords, stride 12B -> 12 lines/instr = data footprint) + mask (coalesced)
        const int j2 = j0 + t;
        const float xj2 = pos[3 * j2 + 0], yj2 = pos[3 * j2 + 1], zj2 = pos[3 * j2 + 2];
        const float ex = xi - xj2, ey = yi - yj2, ez = zi - zj2;
        float e2;
        {
#pragma clang fp contract(off)
            e2 = (ex * ex + ey * ey) + ez * ez;
        }
        const float ed = sqrtf(e2);
        const bool m2 = (ed < RCUT) && (i != j2);
        float ox = 0.0f, oy = 0.0f, oz = 0.0f, mv = 0.0f;
        if (m2) { ox = ex / ed; oy = ey / ed; oz = ez / ed; mv = 1.0f; }
        const long long pair2 = (long long)i * NATOMS + j2;
        float* __restrict__ dir = out + (long long)NATOMS * NATOMS * NBASIS + pair2 * 3;
        float* __restrict__ mk  = out + (long long)NATOMS * NATOMS * (NBASIS + 3) + pair2;
        dir[0] = ox; dir[1] = oy; dir[2] = oz;
        *mk = mv;
    }
}

extern "C" void kernel_launch(void* const* d_in, const int* in_sizes, int n_in,
                              void* d_out, int out_size, void* d_ws, size_t ws_size,
                              hipStream_t stream) {
    const float* pos = (const float*)d_in[0];
    float* out = (float*)d_out;
    // 2048 rows * 32 blocks/row, 320 threads (64 pairs x 5) per block
    edge_embed_kernel<<<dim3(NATOMS * (NATOMS / PAIRS_PER_BLOCK)), dim3(BLOCK_THREADS), 0, stream>>>(pos, out);
}